// Round 13
// baseline (208.111 us; speedup 1.0000x reference)
//
#include <hip/hip_runtime.h>

typedef __attribute__((ext_vector_type(4))) float f32x4;
typedef __attribute__((ext_vector_type(8))) short short8;
typedef unsigned short ushort_t;
typedef unsigned int uint_t;

#define R_  32768
#define L_  6
#define EPS_ 1e-5f

// fragment-ordered weights in workspace (quarter-f layout):
//  w1s [L][4 qt][4 wv][3 ft][6 kc][512]   (A-frags 16f x 32k)  f = qt*192+wv*48+ft*16
//  w2s [L][4 qt][4 wv][3 ei][6 kc2][512]  (A-frags 16e x 32f)  k = qt*192+kc2*32
//  wfr [6 vt][6 kc][512]                  (A-frags 16v x 32k)
#define NW_ 884736

__device__ __forceinline__ ushort_t f2bf(float f) {
    uint_t i = __builtin_bit_cast(uint_t, f);
    uint_t r = (i + 0x7fffu + ((i >> 16) & 1u)) >> 16;   // RNE
    return (ushort_t)r;
}
__device__ __forceinline__ uint_t cvtpk(float a, float b) {
    uint_t r;
    asm("v_cvt_pk_bf16_f32 %0, %1, %2" : "=v"(r) : "v"(a), "v"(b));
    return r;
}

// ---------------- weight convert: per-wave-slice fragment-ordered ----------------
__global__ void wconv_k(const float* __restrict__ W1, const float* __restrict__ W2,
                        const float* __restrict__ Wf,
                        ushort_t* __restrict__ w1s, ushort_t* __restrict__ w2s,
                        ushort_t* __restrict__ wfr)
{
    int i = blockIdx.x * 256 + threadIdx.x;
    if (i < NW_) {    // w1 frags: q = ((l*4+qt)*4+wv)*18 + ft*6 + kc
        int j = i & 7, li = (i >> 3) & 63, q = i >> 9;
        int kc = q % 6; q /= 6;
        int ft = q % 3; q /= 3;
        int wv = q & 3; q >>= 2;
        int qt = q & 3; int l = q >> 2;
        int f = qt * 192 + wv * 48 + ft * 16 + (li & 15);
        int k = kc * 32 + ((li >> 4) << 3) + j;
        w1s[i] = f2bf(W1[((size_t)l * 192 + k) * 768 + f]);
        return;
    }
    i -= NW_;
    if (i < NW_) {    // w2 frags: q = ((l*4+qt)*4+wv)*18 + ei*6 + kc2
        int j = i & 7, li = (i >> 3) & 63, q = i >> 9;
        int kc2 = q % 6; q /= 6;
        int ei = q % 3; q /= 3;
        int wv = q & 3; q >>= 2;
        int qt = q & 3; int l = q >> 2;
        int e = (wv + 4 * ei) * 16 + (li & 15);
        int k = qt * 192 + kc2 * 32 + ((li >> 4) << 3) + j;
        w2s[i] = f2bf(W2[((size_t)l * 768 + k) * 192 + e]);
        return;
    }
    i -= NW_;
    if (i < 36 * 512) {   // head frags: q = vt*6+kc
        int j = i & 7, li = (i >> 3) & 63, q = i >> 9;
        int kc = q % 6, vt = q / 6;
        int v = vt * 16 + (li & 15);
        int k = kc * 32 + ((li >> 4) << 3) + j;
        wfr[i] = f2bf(Wf[(size_t)k * 96 + v]);
    }
}

// ---------------- whole network: block-cooperative, 64 rows/block, 3 blocks/CU ----------------
__global__ __launch_bounds__(256, 3) void net_k(
    const int* __restrict__ idxp, const int* __restrict__ tgp,
    const float* __restrict__ tok, const float* __restrict__ pos,
    const float* __restrict__ ln1g, const float* __restrict__ ln1b,
    const float* __restrict__ ln2g, const float* __restrict__ ln2b,
    const float* __restrict__ b1g, const float* __restrict__ b2g,
    const float* __restrict__ fng, const float* __restrict__ fnb,
    const float* __restrict__ bfb,
    const ushort_t* __restrict__ w1s, const ushort_t* __restrict__ w2s,
    const ushort_t* __restrict__ wfr,
    float* __restrict__ pred, float* __restrict__ partial)
{
    __shared__ __align__(16) ushort_t xb[6 * 4 * 512];     // x B-frags [kc][rg][512] 24KB
    __shared__ __align__(16) ushort_t hbl[6 * 4 * 512];    // h B-frags (one 192-f quarter) 24KB
    __shared__ __align__(16) float lnS1[64][4], lnQ1[64][4];
    __shared__ __align__(16) float lnS2[64][4], lnQ2[64][4];
    __shared__ float lsred[4];

    const int tid = threadIdx.x, lane = tid & 63, w = tid >> 6;
    const int c = lane & 15, g = lane >> 4;
    const int row0 = blockIdx.x * 64;

    // x state distributed: wave w owns e-tiles {w, w+4, w+8}; D-layout
    f32x4 xac[3][4];

    // ---- embedding (no LDS touched yet -> no barrier) ----
#pragma unroll
    for (int rg = 0; rg < 4; ++rg) {
        int row = row0 + rg * 16 + c;
        int id = idxp[row];
        int tt = row & 127;
#pragma unroll
        for (int i = 0; i < 3; ++i) {
            int e0 = (w + 4 * i) * 16 + g * 4;
            float4 a = *(const float4*)(tok + (size_t)id * 192 + e0);
            float4 b = *(const float4*)(pos + (size_t)tt * 192 + e0);
            xac[i][rg][0] = a.x + b.x; xac[i][rg][1] = a.y + b.y;
            xac[i][rg][2] = a.z + b.z; xac[i][rg][3] = a.w + b.w;
        }
    }

#pragma unroll 1
    for (int l = 0; l < L_; ++l) {
        // ---- LN1 stats (cross-wave via LDS) ----
#pragma unroll
        for (int rg = 0; rg < 4; ++rg) {
            float s = 0.f, sq = 0.f;
#pragma unroll
            for (int i = 0; i < 3; ++i)
#pragma unroll
                for (int r = 0; r < 4; ++r) { float v = xac[i][rg][r]; s += v; sq += v * v; }
            s += __shfl_xor(s, 16); sq += __shfl_xor(sq, 16);
            s += __shfl_xor(s, 32); sq += __shfl_xor(sq, 32);
            if (g == 0) { lnS1[rg * 16 + c][w] = s; lnQ1[rg * 16 + c][w] = sq; }
        }
        __syncthreads();
        // ---- apply LN1, compute LN2 stats ----
#pragma unroll
        for (int rg = 0; rg < 4; ++rg) {
            float4 S = *(const float4*)lnS1[rg * 16 + c];
            float4 Q = *(const float4*)lnQ1[rg * 16 + c];
            float mu = (S.x + S.y + S.z + S.w) * (1.f / 192.f);
            float var = (Q.x + Q.y + Q.z + Q.w) * (1.f / 192.f) - mu * mu;
            float ri = rsqrtf(var + EPS_);
            float s2 = 0.f, q2 = 0.f;
#pragma unroll
            for (int i = 0; i < 3; ++i) {
                int e0 = (w + 4 * i) * 16 + g * 4;
                float4 gg = *(const float4*)(ln1g + l * 192 + e0);
                float4 bb = *(const float4*)(ln1b + l * 192 + e0);
                float n0 = (xac[i][rg][0] - mu) * ri * gg.x + bb.x;
                float n1 = (xac[i][rg][1] - mu) * ri * gg.y + bb.y;
                float n2 = (xac[i][rg][2] - mu) * ri * gg.z + bb.z;
                float n3 = (xac[i][rg][3] - mu) * ri * gg.w + bb.w;
                xac[i][rg][0] = n0; xac[i][rg][1] = n1; xac[i][rg][2] = n2; xac[i][rg][3] = n3;
                s2 += n0 + n1 + n2 + n3;
                q2 += n0 * n0 + n1 * n1 + n2 * n2 + n3 * n3;
            }
            s2 += __shfl_xor(s2, 16); q2 += __shfl_xor(q2, 16);
            s2 += __shfl_xor(s2, 32); q2 += __shfl_xor(q2, 32);
            if (g == 0) { lnS2[rg * 16 + c][w] = s2; lnQ2[rg * 16 + c][w] = q2; }
        }
        __syncthreads();
        // ---- apply LN2, pack n2 -> xb B-frags, init accumulator with b2 ----
#pragma unroll
        for (int rg = 0; rg < 4; ++rg) {
            float4 S = *(const float4*)lnS2[rg * 16 + c];
            float4 Q = *(const float4*)lnQ2[rg * 16 + c];
            float mu = (S.x + S.y + S.z + S.w) * (1.f / 192.f);
            float var = (Q.x + Q.y + Q.z + Q.w) * (1.f / 192.f) - mu * mu;
            float ri = rsqrtf(var + EPS_);
#pragma unroll
            for (int i = 0; i < 3; ++i) {
                int et = w + 4 * i;
                int e0 = et * 16 + g * 4;
                float4 gg = *(const float4*)(ln2g + l * 192 + e0);
                float4 bb = *(const float4*)(ln2b + l * 192 + e0);
                float y0 = (xac[i][rg][0] - mu) * ri * gg.x + bb.x;
                float y1 = (xac[i][rg][1] - mu) * ri * gg.y + bb.y;
                float y2 = (xac[i][rg][2] - mu) * ri * gg.z + bb.z;
                float y3 = (xac[i][rg][3] - mu) * ri * gg.w + bb.w;
                uint_t d0 = cvtpk(y0, y1), d1 = cvtpk(y2, y3);
                int kc = et >> 1, floc = ((et & 1) << 4) + g * 4;
                int us = (kc * 4 + rg) * 512 + ((floc >> 3) * 16 + c) * 8 + (floc & 7);
                *(uint2*)(xb + us) = make_uint2(d0, d1);
                // init accumulator with bias2 (replaces end-of-layer bias add)
                float4 b2v = *(const float4*)(b2g + l * 192 + e0);
                xac[i][rg][0] = b2v.x; xac[i][rg][1] = b2v.y;
                xac[i][rg][2] = b2v.z; xac[i][rg][3] = b2v.w;
            }
        }
        __syncthreads();

        // ---- FFN: four 192-f quarters ----
#pragma unroll 1
        for (int qt = 0; qt < 4; ++qt) {
            // gemm1: wave's 48-f slice of this quarter, weights global->reg, x from LDS
            const ushort_t* w1p = w1s + ((size_t)((l * 4 + qt) * 4 + w) * 18) * 512 + lane * 8;
            short8 wa[18];
#pragma unroll
            for (int q = 0; q < 18; ++q) wa[q] = *(const short8*)(w1p + q * 512);
            float4 bbv[3];
#pragma unroll
            for (int f3 = 0; f3 < 3; ++f3)
                bbv[f3] = *(const float4*)(b1g + l * 768 + qt * 192 + w * 48 + f3 * 16 + g * 4);
#pragma unroll
            for (int rg = 0; rg < 4; ++rg) {
                short8 xbf[6];
#pragma unroll
                for (int kc = 0; kc < 6; ++kc)
                    xbf[kc] = *(const short8*)(xb + (kc * 4 + rg) * 512 + lane * 8);
#pragma unroll
                for (int ft = 0; ft < 3; ++ft) {
                    // bias preloaded into the accumulator (C-in of MFMA)
                    f32x4 acc;
                    acc[0] = bbv[ft].x; acc[1] = bbv[ft].y;
                    acc[2] = bbv[ft].z; acc[3] = bbv[ft].w;
                    __builtin_amdgcn_s_setprio(1);
#pragma unroll
                    for (int kc = 0; kc < 6; ++kc)
                        acc = __builtin_amdgcn_mfma_f32_16x16x32_bf16(wa[ft * 6 + kc], xbf[kc], acc, 0, 0, 0);
                    __builtin_amdgcn_s_setprio(0);
                    float y0 = fmaxf(acc[0], 0.f);
                    float y1 = fmaxf(acc[1], 0.f);
                    float y2 = fmaxf(acc[2], 0.f);
                    float y3 = fmaxf(acc[3], 0.f);
                    uint_t d0 = cvtpk(y0, y1), d1 = cvtpk(y2, y3);
                    int fg = w * 48 + ft * 16;           // f within quarter
                    int kc2 = fg >> 5;
                    int floc = (fg & 31) + g * 4;
                    int us = (kc2 * 4 + rg) * 512 + ((floc >> 3) * 16 + c) * 8 + (floc & 7);
                    *(uint2*)(hbl + us) = make_uint2(d0, d1);
                }
            }
            __syncthreads();

            // gemm2: wave's 48-e slice over this quarter's 192 k, weights global->reg
            const ushort_t* w2p = w2s + ((size_t)((l * 4 + qt) * 4 + w) * 18) * 512 + lane * 8;
            short8 wr[18];
#pragma unroll
            for (int q = 0; q < 18; ++q) wr[q] = *(const short8*)(w2p + q * 512);
#pragma unroll
            for (int rg = 0; rg < 4; ++rg) {
                short8 hbf[6];
#pragma unroll
                for (int k6 = 0; k6 < 6; ++k6)
                    hbf[k6] = *(const short8*)(hbl + (k6 * 4 + rg) * 512 + lane * 8);
                __builtin_amdgcn_s_setprio(1);
#pragma unroll
                for (int ei = 0; ei < 3; ++ei)
#pragma unroll
                    for (int k6 = 0; k6 < 6; ++k6)
                        xac[ei][rg] = __builtin_amdgcn_mfma_f32_16x16x32_bf16(wr[ei * 6 + k6], hbf[k6], xac[ei][rg], 0, 0, 0);
                __builtin_amdgcn_s_setprio(0);
            }
            // WAR: next quarter's gemm1 overwrites hbl; last quarter's next
            // hbl write is 3 LN barriers away -> skip
            if (qt < 3) __syncthreads();
        }
        // (bias2 already in accumulator via init)
    }

    // ---- final LN (single) ----
#pragma unroll
    for (int rg = 0; rg < 4; ++rg) {
        float s = 0.f, sq = 0.f;
#pragma unroll
        for (int i = 0; i < 3; ++i)
#pragma unroll
            for (int r = 0; r < 4; ++r) { float v = xac[i][rg][r]; s += v; sq += v * v; }
        s += __shfl_xor(s, 16); sq += __shfl_xor(sq, 16);
        s += __shfl_xor(s, 32); sq += __shfl_xor(sq, 32);
        if (g == 0) { lnS1[rg * 16 + c][w] = s; lnQ1[rg * 16 + c][w] = sq; }
    }
    __syncthreads();
#pragma unroll
    for (int rg = 0; rg < 4; ++rg) {
        float4 S = *(const float4*)lnS1[rg * 16 + c];
        float4 Q = *(const float4*)lnQ1[rg * 16 + c];
        float mu = (S.x + S.y + S.z + S.w) * (1.f / 192.f);
        float var = (Q.x + Q.y + Q.z + Q.w) * (1.f / 192.f) - mu * mu;
        float ri = rsqrtf(var + EPS_);
#pragma unroll
        for (int i = 0; i < 3; ++i) {
            int et = w + 4 * i;
            int e0 = et * 16 + g * 4;
            float4 gg = *(const float4*)(fng + e0);
            float4 bb = *(const float4*)(fnb + e0);
            float y0 = (xac[i][rg][0] - mu) * ri * gg.x + bb.x;
            float y1 = (xac[i][rg][1] - mu) * ri * gg.y + bb.y;
            float y2 = (xac[i][rg][2] - mu) * ri * gg.z + bb.z;
            float y3 = (xac[i][rg][3] - mu) * ri * gg.w + bb.w;
            uint_t d0 = cvtpk(y0, y1), d1 = cvtpk(y2, y3);
            int kc = et >> 1, floc = ((et & 1) << 4) + g * 4;
            int us = (kc * 4 + rg) * 512 + ((floc >> 3) * 16 + c) * 8 + (floc & 7);
            *(uint2*)(xb + us) = make_uint2(d0, d1);
        }
    }
    __syncthreads();

    // ---- head: wave w handles rows rg=w (16 rows); vocab in 2 batches of 3 tiles ----
    short8 xbf[6];
#pragma unroll
    for (int kc = 0; kc < 6; ++kc)
        xbf[kc] = *(const short8*)(xb + (kc * 4 + w) * 512 + lane * 8);
    f32x4 av[6];
#pragma unroll
    for (int grp = 0; grp < 2; ++grp) {
        short8 wfh[18];
        const ushort_t* wfp = wfr + (size_t)grp * 18 * 512 + lane * 8;
#pragma unroll
        for (int q = 0; q < 18; ++q) wfh[q] = *(const short8*)(wfp + q * 512);
        __builtin_amdgcn_s_setprio(1);
#pragma unroll
        for (int vt3 = 0; vt3 < 3; ++vt3) {
            f32x4 acc = {};
#pragma unroll
            for (int kc = 0; kc < 6; ++kc)
                acc = __builtin_amdgcn_mfma_f32_16x16x32_bf16(wfh[vt3 * 6 + kc], xbf[kc], acc, 0, 0, 0);
            av[grp * 3 + vt3] = acc;
        }
        __builtin_amdgcn_s_setprio(0);
    }

    float vv[6][4];
#pragma unroll
    for (int vt = 0; vt < 6; ++vt) {
        float4 bb = *(const float4*)(bfb + vt * 16 + g * 4);
        vv[vt][0] = av[vt][0] + bb.x;
        vv[vt][1] = av[vt][1] + bb.y;
        vv[vt][2] = av[vt][2] + bb.z;
        vv[vt][3] = av[vt][3] + bb.w;
    }
    float mx = -1e30f;
#pragma unroll
    for (int vt = 0; vt < 6; ++vt)
#pragma unroll
        for (int r = 0; r < 4; ++r) mx = fmaxf(mx, vv[vt][r]);
    mx = fmaxf(mx, __shfl_xor(mx, 16));
    mx = fmaxf(mx, __shfl_xor(mx, 32));
    float se = 0.f;
#pragma unroll
    for (int vt = 0; vt < 6; ++vt)
#pragma unroll
        for (int r = 0; r < 4; ++r) se += expf(vv[vt][r] - mx);
    se += __shfl_xor(se, 16);
    se += __shfl_xor(se, 32);
    float lse = logf(se) + mx;
    int myrow = row0 + w * 16 + c;
    int tgt = tgp[myrow];
    float lsum = 0.f;
#pragma unroll
    for (int vt = 0; vt < 6; ++vt)
#pragma unroll
        for (int r = 0; r < 4; ++r)
            if (tgt == vt * 16 + g * 4 + r) lsum += lse - vv[vt][r];
#pragma unroll
    for (int vt = 0; vt < 6; ++vt) {
        float4 o;
        o.x = vv[vt][0]; o.y = vv[vt][1]; o.z = vv[vt][2]; o.w = vv[vt][3];
        *(float4*)(pred + (size_t)myrow * 96 + vt * 16 + g * 4) = o;
    }
#pragma unroll
    for (int m = 1; m < 64; m <<= 1) lsum += __shfl_xor(lsum, m);
    if (lane == 0) lsred[w] = lsum;
    __syncthreads();
    if (tid == 0) partial[blockIdx.x] = lsred[0] + lsred[1] + lsred[2] + lsred[3];
}

__global__ void lossred_k(const float* __restrict__ partial, float* __restrict__ out)
{
    __shared__ double sd[256];
    int t = threadIdx.x;
    sd[t] = (double)partial[t] + (double)partial[t + 256];
    __syncthreads();
    for (int s = 128; s > 0; s >>= 1) {
        if (t < s) sd[t] += sd[t + s];
        __syncthreads();
    }
    if (t == 0) out[0] = (float)(sd[0] / (double)R_);
}

extern "C" void kernel_launch(void* const* d_in, const int* in_sizes, int n_in,
                              void* d_out, int out_size, void* d_ws, size_t ws_size,
                              hipStream_t stream)
{
    (void)in_sizes; (void)n_in; (void)out_size; (void)ws_size;
    const int*   index   = (const int*)  d_in[0];
    const int*   targets = (const int*)  d_in[1];
    const float* tok     = (const float*)d_in[2];
    const float* pos     = (const float*)d_in[3];
    const float* ln1g    = (const float*)d_in[4];
    const float* ln1b    = (const float*)d_in[5];
    const float* ln2g    = (const float*)d_in[6];
    const float* ln2b    = (const float*)d_in[7];
    // d_in[8..10] = Wq/Wk/Wv: dead in the reference forward
    const float* W1      = (const float*)d_in[11];
    const float* b1      = (const float*)d_in[12];
    const float* W2      = (const float*)d_in[13];
    const float* b2      = (const float*)d_in[14];
    const float* fng     = (const float*)d_in[15];
    const float* fnb     = (const float*)d_in[16];
    const float* Wf      = (const float*)d_in[17];
    const float* bfv     = (const float*)d_in[18];

    ushort_t* w1s = (ushort_t*)d_ws;                        // [884736]
    ushort_t* w2s = w1s + NW_;                              // [884736]
    ushort_t* wfr = w2s + NW_;                              // [18432]
    float* partial = (float*)(wfr + 36 * 512);              // [512]
    float* pred  = (float*)d_out;
    float* lossp = pred + (size_t)R_ * 96;

    const int nconv = 2 * NW_ + 36 * 512;                   // 1787904 = 6984*256
    wconv_k<<<nconv / 256, 256, 0, stream>>>(W1, W2, Wf, w1s, w2s, wfr);
    net_k<<<512, 256, 0, stream>>>(index, targets, tok, pos, ln1g, ln1b, ln2g, ln2b,
                                   b1, b2, fng, fnb, bfv, w1s, w2s, wfr, pred, partial);
    lossred_k<<<1, 256, 0, stream>>>(partial, lossp);
}

// Round 14
// 198.992 us; speedup vs baseline: 1.0458x; 1.0458x over previous
//
#include <hip/hip_runtime.h>

typedef __attribute__((ext_vector_type(4))) float f32x4;
typedef __attribute__((ext_vector_type(8))) short short8;
typedef unsigned short ushort_t;
typedef unsigned int uint_t;

#define R_  32768
#define L_  6
#define EPS_ 1e-5f

// fragment-ordered weights in workspace (quarter-f layout):
//  w1s [L][4 qt][4 wv][3 ft][6 kc][512]   (A-frags 16f x 32k)  f = qt*192+wv*48+ft*16
//  w2s [L][4 qt][4 wv][3 ei][6 kc2][512]  (A-frags 16e x 32f)  k = qt*192+kc2*32
//  wfr [6 vt][6 kc][512]                  (A-frags 16v x 32k)
#define NW_ 884736

__device__ __forceinline__ ushort_t f2bf(float f) {
    uint_t i = __builtin_bit_cast(uint_t, f);
    uint_t r = (i + 0x7fffu + ((i >> 16) & 1u)) >> 16;   // RNE
    return (ushort_t)r;
}
__device__ __forceinline__ uint_t cvtpk(float a, float b) {
    uint_t r;
    asm("v_cvt_pk_bf16_f32 %0, %1, %2" : "=v"(r) : "v"(a), "v"(b));
    return r;
}

// ---------------- weight convert: per-wave-slice fragment-ordered ----------------
__global__ void wconv_k(const float* __restrict__ W1, const float* __restrict__ W2,
                        const float* __restrict__ Wf,
                        ushort_t* __restrict__ w1s, ushort_t* __restrict__ w2s,
                        ushort_t* __restrict__ wfr)
{
    int i = blockIdx.x * 256 + threadIdx.x;
    if (i < NW_) {    // w1 frags: q = ((l*4+qt)*4+wv)*18 + ft*6 + kc
        int j = i & 7, li = (i >> 3) & 63, q = i >> 9;
        int kc = q % 6; q /= 6;
        int ft = q % 3; q /= 3;
        int wv = q & 3; q >>= 2;
        int qt = q & 3; int l = q >> 2;
        int f = qt * 192 + wv * 48 + ft * 16 + (li & 15);
        int k = kc * 32 + ((li >> 4) << 3) + j;
        w1s[i] = f2bf(W1[((size_t)l * 192 + k) * 768 + f]);
        return;
    }
    i -= NW_;
    if (i < NW_) {    // w2 frags: q = ((l*4+qt)*4+wv)*18 + ei*6 + kc2
        int j = i & 7, li = (i >> 3) & 63, q = i >> 9;
        int kc2 = q % 6; q /= 6;
        int ei = q % 3; q /= 3;
        int wv = q & 3; q >>= 2;
        int qt = q & 3; int l = q >> 2;
        int e = (wv + 4 * ei) * 16 + (li & 15);
        int k = qt * 192 + kc2 * 32 + ((li >> 4) << 3) + j;
        w2s[i] = f2bf(W2[((size_t)l * 768 + k) * 192 + e]);
        return;
    }
    i -= NW_;
    if (i < 36 * 512) {   // head frags: q = vt*6+kc
        int j = i & 7, li = (i >> 3) & 63, q = i >> 9;
        int kc = q % 6, vt = q / 6;
        int v = vt * 16 + (li & 15);
        int k = kc * 32 + ((li >> 4) << 3) + j;
        wfr[i] = f2bf(Wf[(size_t)k * 96 + v]);
    }
}

// ---------------- whole network: block-cooperative, 32 rows/block ----------------
__global__ __launch_bounds__(256, 3) void net_k(
    const int* __restrict__ idxp, const int* __restrict__ tgp,
    const float* __restrict__ tok, const float* __restrict__ pos,
    const float* __restrict__ ln1g, const float* __restrict__ ln1b,
    const float* __restrict__ ln2g, const float* __restrict__ ln2b,
    const float* __restrict__ b1g, const float* __restrict__ b2g,
    const float* __restrict__ fng, const float* __restrict__ fnb,
    const float* __restrict__ bfb,
    const ushort_t* __restrict__ w1s, const ushort_t* __restrict__ w2s,
    const ushort_t* __restrict__ wfr,
    float* __restrict__ pred, float* __restrict__ partial)
{
    __shared__ __align__(16) ushort_t xb[6 * 2 * 512];     // x B-frags [kc][rg][512] 12KB
    __shared__ __align__(16) ushort_t hbl[6 * 2 * 512];    // h quarter B-frags 12KB
    __shared__ __align__(16) float lnS1[32][4], lnQ1[32][4];
    __shared__ __align__(16) float lnS2[32][4], lnQ2[32][4];
    __shared__ float smx[2][32], sse[2][32];
    __shared__ float lsred[4];

    const int tid = threadIdx.x, lane = tid & 63, w = tid >> 6;
    const int c = lane & 15, g = lane >> 4;
    const int row0 = blockIdx.x * 32;

    // x state distributed: wave w owns e-tiles {w, w+4, w+8}, rows rg*16+c (rg<2)
    f32x4 xac[3][2];

    // ---- embedding ----
#pragma unroll
    for (int rg = 0; rg < 2; ++rg) {
        int row = row0 + rg * 16 + c;
        int id = idxp[row];
        int tt = row & 127;
#pragma unroll
        for (int i = 0; i < 3; ++i) {
            int e0 = (w + 4 * i) * 16 + g * 4;
            float4 a = *(const float4*)(tok + (size_t)id * 192 + e0);
            float4 b = *(const float4*)(pos + (size_t)tt * 192 + e0);
            xac[i][rg][0] = a.x + b.x; xac[i][rg][1] = a.y + b.y;
            xac[i][rg][2] = a.z + b.z; xac[i][rg][3] = a.w + b.w;
        }
    }

#pragma unroll 1
    for (int l = 0; l < L_; ++l) {
        // ---- LN1 stats (cross-wave via LDS) ----
#pragma unroll
        for (int rg = 0; rg < 2; ++rg) {
            float s = 0.f, sq = 0.f;
#pragma unroll
            for (int i = 0; i < 3; ++i)
#pragma unroll
                for (int r = 0; r < 4; ++r) { float v = xac[i][rg][r]; s += v; sq += v * v; }
            s += __shfl_xor(s, 16); sq += __shfl_xor(sq, 16);
            s += __shfl_xor(s, 32); sq += __shfl_xor(sq, 32);
            if (g == 0) { lnS1[rg * 16 + c][w] = s; lnQ1[rg * 16 + c][w] = sq; }
        }
        __syncthreads();
        // ---- apply LN1, compute LN2 stats ----
#pragma unroll
        for (int rg = 0; rg < 2; ++rg) {
            float4 S = *(const float4*)lnS1[rg * 16 + c];
            float4 Q = *(const float4*)lnQ1[rg * 16 + c];
            float mu = (S.x + S.y + S.z + S.w) * (1.f / 192.f);
            float var = (Q.x + Q.y + Q.z + Q.w) * (1.f / 192.f) - mu * mu;
            float ri = rsqrtf(var + EPS_);
            float s2 = 0.f, q2 = 0.f;
#pragma unroll
            for (int i = 0; i < 3; ++i) {
                int e0 = (w + 4 * i) * 16 + g * 4;
                float4 gg = *(const float4*)(ln1g + l * 192 + e0);
                float4 bb = *(const float4*)(ln1b + l * 192 + e0);
                float n0 = (xac[i][rg][0] - mu) * ri * gg.x + bb.x;
                float n1 = (xac[i][rg][1] - mu) * ri * gg.y + bb.y;
                float n2 = (xac[i][rg][2] - mu) * ri * gg.z + bb.z;
                float n3 = (xac[i][rg][3] - mu) * ri * gg.w + bb.w;
                xac[i][rg][0] = n0; xac[i][rg][1] = n1; xac[i][rg][2] = n2; xac[i][rg][3] = n3;
                s2 += n0 + n1 + n2 + n3;
                q2 += n0 * n0 + n1 * n1 + n2 * n2 + n3 * n3;
            }
            s2 += __shfl_xor(s2, 16); q2 += __shfl_xor(q2, 16);
            s2 += __shfl_xor(s2, 32); q2 += __shfl_xor(q2, 32);
            if (g == 0) { lnS2[rg * 16 + c][w] = s2; lnQ2[rg * 16 + c][w] = q2; }
        }
        __syncthreads();
        // ---- apply LN2, pack n2 -> xb B-frags, init accumulator with b2 ----
#pragma unroll
        for (int rg = 0; rg < 2; ++rg) {
            float4 S = *(const float4*)lnS2[rg * 16 + c];
            float4 Q = *(const float4*)lnQ2[rg * 16 + c];
            float mu = (S.x + S.y + S.z + S.w) * (1.f / 192.f);
            float var = (Q.x + Q.y + Q.z + Q.w) * (1.f / 192.f) - mu * mu;
            float ri = rsqrtf(var + EPS_);
#pragma unroll
            for (int i = 0; i < 3; ++i) {
                int et = w + 4 * i;
                int e0 = et * 16 + g * 4;
                float4 gg = *(const float4*)(ln2g + l * 192 + e0);
                float4 bb = *(const float4*)(ln2b + l * 192 + e0);
                float y0 = (xac[i][rg][0] - mu) * ri * gg.x + bb.x;
                float y1 = (xac[i][rg][1] - mu) * ri * gg.y + bb.y;
                float y2 = (xac[i][rg][2] - mu) * ri * gg.z + bb.z;
                float y3 = (xac[i][rg][3] - mu) * ri * gg.w + bb.w;
                uint_t d0 = cvtpk(y0, y1), d1 = cvtpk(y2, y3);
                int kc = et >> 1, floc = ((et & 1) << 4) + g * 4;
                int us = (kc * 2 + rg) * 512 + ((floc >> 3) * 16 + c) * 8 + (floc & 7);
                *(uint2*)(xb + us) = make_uint2(d0, d1);
                float4 b2v = *(const float4*)(b2g + l * 192 + e0);
                xac[i][rg][0] = b2v.x; xac[i][rg][1] = b2v.y;
                xac[i][rg][2] = b2v.z; xac[i][rg][3] = b2v.w;
            }
        }
        __syncthreads();

        // ---- FFN: four 192-f quarters ----
#pragma unroll 1
        for (int qt = 0; qt < 4; ++qt) {
            // hold all x frags for both row groups (12 frags, 48 regs)
            short8 xall[12];
#pragma unroll
            for (int q = 0; q < 12; ++q)
                xall[q] = *(const short8*)(xb + q * 512 + lane * 8);

            // gemm1: wave's 48-f slice, weights in 6-frag bursts
            const ushort_t* w1p = w1s + ((size_t)((l * 4 + qt) * 4 + w) * 18) * 512 + lane * 8;
#pragma unroll
            for (int ft = 0; ft < 3; ++ft) {
                short8 wa6[6];
#pragma unroll
                for (int kc = 0; kc < 6; ++kc)
                    wa6[kc] = *(const short8*)(w1p + (ft * 6 + kc) * 512);
                float4 bbv = *(const float4*)(b1g + l * 768 + qt * 192 + w * 48 + ft * 16 + g * 4);
#pragma unroll
                for (int rg = 0; rg < 2; ++rg) {
                    f32x4 acc;
                    acc[0] = bbv.x; acc[1] = bbv.y; acc[2] = bbv.z; acc[3] = bbv.w;
                    __builtin_amdgcn_s_setprio(1);
#pragma unroll
                    for (int kc = 0; kc < 6; ++kc)
                        acc = __builtin_amdgcn_mfma_f32_16x16x32_bf16(wa6[kc], xall[kc * 2 + rg], acc, 0, 0, 0);
                    __builtin_amdgcn_s_setprio(0);
                    float y0 = fmaxf(acc[0], 0.f);
                    float y1 = fmaxf(acc[1], 0.f);
                    float y2 = fmaxf(acc[2], 0.f);
                    float y3 = fmaxf(acc[3], 0.f);
                    uint_t d0 = cvtpk(y0, y1), d1 = cvtpk(y2, y3);
                    int fg = w * 48 + ft * 16;
                    int kc2 = fg >> 5;
                    int floc = (fg & 31) + g * 4;
                    int us = (kc2 * 2 + rg) * 512 + ((floc >> 3) * 16 + c) * 8 + (floc & 7);
                    *(uint2*)(hbl + us) = make_uint2(d0, d1);
                }
            }
            __syncthreads();

            // gemm2: wave's 48-e slice over this quarter's 192 k
            short8 hq[12];
#pragma unroll
            for (int q = 0; q < 12; ++q)
                hq[q] = *(const short8*)(hbl + q * 512 + lane * 8);
            const ushort_t* w2p = w2s + ((size_t)((l * 4 + qt) * 4 + w) * 18) * 512 + lane * 8;
#pragma unroll
            for (int ei = 0; ei < 3; ++ei) {
                short8 wr6[6];
#pragma unroll
                for (int k6 = 0; k6 < 6; ++k6)
                    wr6[k6] = *(const short8*)(w2p + (ei * 6 + k6) * 512);
                __builtin_amdgcn_s_setprio(1);
#pragma unroll
                for (int rg = 0; rg < 2; ++rg)
#pragma unroll
                    for (int k6 = 0; k6 < 6; ++k6)
                        xac[ei][rg] = __builtin_amdgcn_mfma_f32_16x16x32_bf16(wr6[k6], hq[k6 * 2 + rg], xac[ei][rg], 0, 0, 0);
                __builtin_amdgcn_s_setprio(0);
            }
            // WAR on hbl before next quarter's gemm1; last quarter's next
            // hbl write is 3 LN barriers away -> skip
            if (qt < 3) __syncthreads();
        }
    }

    // ---- final LN (single) ----
#pragma unroll
    for (int rg = 0; rg < 2; ++rg) {
        float s = 0.f, sq = 0.f;
#pragma unroll
        for (int i = 0; i < 3; ++i)
#pragma unroll
            for (int r = 0; r < 4; ++r) { float v = xac[i][rg][r]; s += v; sq += v * v; }
        s += __shfl_xor(s, 16); sq += __shfl_xor(sq, 16);
        s += __shfl_xor(s, 32); sq += __shfl_xor(sq, 32);
        if (g == 0) { lnS1[rg * 16 + c][w] = s; lnQ1[rg * 16 + c][w] = sq; }
    }
    __syncthreads();
#pragma unroll
    for (int rg = 0; rg < 2; ++rg) {
        float4 S = *(const float4*)lnS1[rg * 16 + c];
        float4 Q = *(const float4*)lnQ1[rg * 16 + c];
        float mu = (S.x + S.y + S.z + S.w) * (1.f / 192.f);
        float var = (Q.x + Q.y + Q.z + Q.w) * (1.f / 192.f) - mu * mu;
        float ri = rsqrtf(var + EPS_);
#pragma unroll
        for (int i = 0; i < 3; ++i) {
            int et = w + 4 * i;
            int e0 = et * 16 + g * 4;
            float4 gg = *(const float4*)(fng + e0);
            float4 bb = *(const float4*)(fnb + e0);
            float y0 = (xac[i][rg][0] - mu) * ri * gg.x + bb.x;
            float y1 = (xac[i][rg][1] - mu) * ri * gg.y + bb.y;
            float y2 = (xac[i][rg][2] - mu) * ri * gg.z + bb.z;
            float y3 = (xac[i][rg][3] - mu) * ri * gg.w + bb.w;
            uint_t d0 = cvtpk(y0, y1), d1 = cvtpk(y2, y3);
            int kc = et >> 1, floc = ((et & 1) << 4) + g * 4;
            int us = (kc * 2 + rg) * 512 + ((floc >> 3) * 16 + c) * 8 + (floc & 7);
            *(uint2*)(xb + us) = make_uint2(d0, d1);
        }
    }
    __syncthreads();

    // ---- head: wave (rg = w&1, vgroup = w>>1) does 16 rows x 48 vocab ----
    const int hrg = w & 1, vg = w >> 1;
    short8 xbf[6];
#pragma unroll
    for (int kc = 0; kc < 6; ++kc)
        xbf[kc] = *(const short8*)(xb + (kc * 2 + hrg) * 512 + lane * 8);
    short8 wfh[18];
    {
        const ushort_t* wfp = wfr + (size_t)vg * 18 * 512 + lane * 8;
#pragma unroll
        for (int q = 0; q < 18; ++q) wfh[q] = *(const short8*)(wfp + q * 512);
    }
    f32x4 av[3];
    __builtin_amdgcn_s_setprio(1);
#pragma unroll
    for (int vt3 = 0; vt3 < 3; ++vt3) {
        f32x4 acc = {};
#pragma unroll
        for (int kc = 0; kc < 6; ++kc)
            acc = __builtin_amdgcn_mfma_f32_16x16x32_bf16(wfh[vt3 * 6 + kc], xbf[kc], acc, 0, 0, 0);
        av[vt3] = acc;
    }
    __builtin_amdgcn_s_setprio(0);

    float vv[3][4];
#pragma unroll
    for (int vt3 = 0; vt3 < 3; ++vt3) {
        float4 bb = *(const float4*)(bfb + (vg * 3 + vt3) * 16 + g * 4);
        vv[vt3][0] = av[vt3][0] + bb.x;
        vv[vt3][1] = av[vt3][1] + bb.y;
        vv[vt3][2] = av[vt3][2] + bb.z;
        vv[vt3][3] = av[vt3][3] + bb.w;
    }
    float mx = -1e30f;
#pragma unroll
    for (int vt3 = 0; vt3 < 3; ++vt3)
#pragma unroll
        for (int r = 0; r < 4; ++r) mx = fmaxf(mx, vv[vt3][r]);
    mx = fmaxf(mx, __shfl_xor(mx, 16));
    mx = fmaxf(mx, __shfl_xor(mx, 32));
    float se = 0.f;
#pragma unroll
    for (int vt3 = 0; vt3 < 3; ++vt3)
#pragma unroll
        for (int r = 0; r < 4; ++r) se += expf(vv[vt3][r] - mx);
    se += __shfl_xor(se, 16);
    se += __shfl_xor(se, 32);
    if (g == 0) { smx[vg][hrg * 16 + c] = mx; sse[vg][hrg * 16 + c] = se; }
    __syncthreads();
    // combine the two vocab halves for this row
    float m0 = smx[0][hrg * 16 + c], m1 = smx[1][hrg * 16 + c];
    float e0s = sse[0][hrg * 16 + c], e1s = sse[1][hrg * 16 + c];
    float mm = fmaxf(m0, m1);
    float set = e0s * expf(m0 - mm) + e1s * expf(m1 - mm);
    float lse = logf(set) + mm;

    int myrow = row0 + hrg * 16 + c;
    int tgt = tgp[myrow];
    float lsum = 0.f;
#pragma unroll
    for (int vt3 = 0; vt3 < 3; ++vt3)
#pragma unroll
        for (int r = 0; r < 4; ++r)
            if (tgt == (vg * 3 + vt3) * 16 + g * 4 + r) lsum += lse - vv[vt3][r];
#pragma unroll
    for (int vt3 = 0; vt3 < 3; ++vt3) {
        float4 o;
        o.x = vv[vt3][0]; o.y = vv[vt3][1]; o.z = vv[vt3][2]; o.w = vv[vt3][3];
        *(float4*)(pred + (size_t)myrow * 96 + (vg * 3 + vt3) * 16 + g * 4) = o;
    }
#pragma unroll
    for (int m = 1; m < 64; m <<= 1) lsum += __shfl_xor(lsum, m);
    if (lane == 0) lsred[w] = lsum;
    __syncthreads();
    if (tid == 0) partial[blockIdx.x] = lsred[0] + lsred[1] + lsred[2] + lsred[3];
}

__global__ void lossred_k(const float* __restrict__ partial, float* __restrict__ out)
{
    __shared__ double sd[256];
    int t = threadIdx.x;
    sd[t] = (double)partial[t] + (double)partial[t + 256]
          + (double)partial[t + 512] + (double)partial[t + 768];
    __syncthreads();
    for (int s = 128; s > 0; s >>= 1) {
        if (t < s) sd[t] += sd[t + s];
        __syncthreads();
    }
    if (t == 0) out[0] = (float)(sd[0] / (double)R_);
}

extern "C" void kernel_launch(void* const* d_in, const int* in_sizes, int n_in,
                              void* d_out, int out_size, void* d_ws, size_t ws_size,
                              hipStream_t stream)
{
    (void)in_sizes; (void)n_in; (void)out_size; (void)ws_size;
    const int*   index   = (const int*)  d_in[0];
    const int*   targets = (const int*)  d_in[1];
    const float* tok     = (const float*)d_in[2];
    const float* pos     = (const float*)d_in[3];
    const float* ln1g    = (const float*)d_in[4];
    const float* ln1b    = (const float*)d_in[5];
    const float* ln2g    = (const float*)d_in[6];
    const float* ln2b    = (const float*)d_in[7];
    // d_in[8..10] = Wq/Wk/Wv: dead in the reference forward
    const float* W1      = (const float*)d_in[11];
    const float* b1      = (const float*)d_in[12];
    const float* W2      = (const float*)d_in[13];
    const float* b2      = (const float*)d_in[14];
    const float* fng     = (const float*)d_in[15];
    const float* fnb     = (const float*)d_in[16];
    const float* Wf      = (const float*)d_in[17];
    const float* bfv     = (const float*)d_in[18];

    ushort_t* w1s = (ushort_t*)d_ws;                        // [884736]
    ushort_t* w2s = w1s + NW_;                              // [884736]
    ushort_t* wfr = w2s + NW_;                              // [18432]
    float* partial = (float*)(wfr + 36 * 512);              // [1024]
    float* pred  = (float*)d_out;
    float* lossp = pred + (size_t)R_ * 96;

    const int nconv = 2 * NW_ + 36 * 512;                   // 1787904 = 6984*256
    wconv_k<<<nconv / 256, 256, 0, stream>>>(W1, W2, Wf, w1s, w2s, wfr);
    net_k<<<1024, 256, 0, stream>>>(index, targets, tok, pos, ln1g, ln1b, ln2g, ln2b,
                                    b1, b2, fng, fnb, bfv, w1s, w2s, wfr, pred, partial);
    lossred_k<<<1, 256, 0, stream>>>(partial, lossp);
}

// Round 15
// 148.497 us; speedup vs baseline: 1.4015x; 1.3400x over previous
//
#include <hip/hip_runtime.h>

typedef __attribute__((ext_vector_type(4))) float f32x4;
typedef __attribute__((ext_vector_type(8))) short short8;
typedef unsigned short ushort_t;
typedef unsigned int uint_t;

#define R_  32768
#define L_  6
#define EPS_ 1e-5f

// fragment-ordered weights in workspace:
//  w1s [L][2 half][4 wave][6 ft][6 kc][512]   (A-frags 16f x 32k)
//  w2s [L][2 half][4 wave][3 ei][12 kc2][512] (A-frags 16e x 32f)
//  wfr [6 vt][6 kc][512]                      (A-frags 16v x 32k)
#define NW_ 884736

__device__ __forceinline__ ushort_t f2bf(float f) {
    uint_t i = __builtin_bit_cast(uint_t, f);
    uint_t r = (i + 0x7fffu + ((i >> 16) & 1u)) >> 16;   // RNE
    return (ushort_t)r;
}
__device__ __forceinline__ uint_t cvtpk(float a, float b) {
    uint_t r;
    asm("v_cvt_pk_bf16_f32 %0, %1, %2" : "=v"(r) : "v"(a), "v"(b));
    return r;
}

// ---------------- weight convert: per-wave-slice fragment-ordered ----------------
__global__ void wconv_k(const float* __restrict__ W1, const float* __restrict__ W2,
                        const float* __restrict__ Wf,
                        ushort_t* __restrict__ w1s, ushort_t* __restrict__ w2s,
                        ushort_t* __restrict__ wfr)
{
    int i = blockIdx.x * 256 + threadIdx.x;
    if (i < NW_) {    // w1 frags: global frag q = (((l*2+half)*4+wv)*6+ft)*6+kc
        int j = i & 7, li = (i >> 3) & 63, q = i >> 9;
        int kc = q % 6; q /= 6;
        int ft = q % 6; q /= 6;
        int wv = q & 3; q >>= 2;
        int half = q & 1; int l = q >> 1;
        int f = half * 384 + wv * 96 + ft * 16 + (li & 15);
        int k = kc * 32 + ((li >> 4) << 3) + j;
        w1s[i] = f2bf(W1[((size_t)l * 192 + k) * 768 + f]);
        return;
    }
    i -= NW_;
    if (i < NW_) {    // w2 frags: q = (((l*2+half)*4+wv)*3+ei)*12+kc2
        int j = i & 7, li = (i >> 3) & 63, q = i >> 9;
        int kc2 = q % 12; q /= 12;
        int ei = q % 3; q /= 3;
        int wv = q & 3; q >>= 2;
        int half = q & 1; int l = q >> 1;
        int e = (wv + 4 * ei) * 16 + (li & 15);
        int k = half * 384 + kc2 * 32 + ((li >> 4) << 3) + j;
        w2s[i] = f2bf(W2[((size_t)l * 768 + k) * 192 + e]);
        return;
    }
    i -= NW_;
    if (i < 36 * 512) {   // head frags: q = vt*6+kc
        int j = i & 7, li = (i >> 3) & 63, q = i >> 9;
        int kc = q % 6, vt = q / 6;
        int v = vt * 16 + (li & 15);
        int k = kc * 32 + ((li >> 4) << 3) + j;
        wfr[i] = f2bf(Wf[(size_t)k * 96 + v]);
    }
}

// ---------------- whole network: block-cooperative, 64 rows/block ----------------
__global__ __launch_bounds__(256, 2) void net_k(
    const int* __restrict__ idxp, const int* __restrict__ tgp,
    const float* __restrict__ tok, const float* __restrict__ pos,
    const float* __restrict__ ln1g, const float* __restrict__ ln1b,
    const float* __restrict__ ln2g, const float* __restrict__ ln2b,
    const float* __restrict__ b1g, const float* __restrict__ b2g,
    const float* __restrict__ fng, const float* __restrict__ fnb,
    const float* __restrict__ bfb,
    const ushort_t* __restrict__ w1s, const ushort_t* __restrict__ w2s,
    const ushort_t* __restrict__ wfr,
    float* __restrict__ pred, float* __restrict__ partial)
{
    __shared__ __align__(16) ushort_t xb[6 * 4 * 512];     // x B-frags  [kc][rg][512] 24KB
    __shared__ __align__(16) ushort_t hbl[12 * 4 * 512];   // h B-frags  [kc2][rg][512] 48KB
    __shared__ __align__(16) float lnS1[64][4], lnQ1[64][4];
    __shared__ __align__(16) float lnS2[64][4], lnQ2[64][4];
    __shared__ float lsred[4];

    const int tid = threadIdx.x, lane = tid & 63, w = tid >> 6;
    const int c = lane & 15, g = lane >> 4;
    const int row0 = blockIdx.x * 64;

    // x state distributed: wave w owns e-tiles {w, w+4, w+8}; D-layout
    f32x4 xac[3][4];

    // ---- embedding (no LDS touched yet -> no barrier) ----
#pragma unroll
    for (int rg = 0; rg < 4; ++rg) {
        int row = row0 + rg * 16 + c;
        int id = idxp[row];
        int tt = row & 127;
#pragma unroll
        for (int i = 0; i < 3; ++i) {
            int e0 = (w + 4 * i) * 16 + g * 4;
            float4 a = *(const float4*)(tok + (size_t)id * 192 + e0);
            float4 b = *(const float4*)(pos + (size_t)tt * 192 + e0);
            xac[i][rg][0] = a.x + b.x; xac[i][rg][1] = a.y + b.y;
            xac[i][rg][2] = a.z + b.z; xac[i][rg][3] = a.w + b.w;
        }
    }

#pragma unroll 1
    for (int l = 0; l < L_; ++l) {
        // ---- LN1 stats (cross-wave via LDS) ----
#pragma unroll
        for (int rg = 0; rg < 4; ++rg) {
            float s = 0.f, sq = 0.f;
#pragma unroll
            for (int i = 0; i < 3; ++i)
#pragma unroll
                for (int r = 0; r < 4; ++r) { float v = xac[i][rg][r]; s += v; sq += v * v; }
            s += __shfl_xor(s, 16); sq += __shfl_xor(sq, 16);
            s += __shfl_xor(s, 32); sq += __shfl_xor(sq, 32);
            if (g == 0) { lnS1[rg * 16 + c][w] = s; lnQ1[rg * 16 + c][w] = sq; }
        }
        __syncthreads();
        // ---- apply LN1, compute LN2 stats ----
#pragma unroll
        for (int rg = 0; rg < 4; ++rg) {
            float4 S = *(const float4*)lnS1[rg * 16 + c];
            float4 Q = *(const float4*)lnQ1[rg * 16 + c];
            float mu = (S.x + S.y + S.z + S.w) * (1.f / 192.f);
            float var = (Q.x + Q.y + Q.z + Q.w) * (1.f / 192.f) - mu * mu;
            float ri = rsqrtf(var + EPS_);
            float s2 = 0.f, q2 = 0.f;
#pragma unroll
            for (int i = 0; i < 3; ++i) {
                int e0 = (w + 4 * i) * 16 + g * 4;
                float4 gg = *(const float4*)(ln1g + l * 192 + e0);
                float4 bb = *(const float4*)(ln1b + l * 192 + e0);
                float n0 = (xac[i][rg][0] - mu) * ri * gg.x + bb.x;
                float n1 = (xac[i][rg][1] - mu) * ri * gg.y + bb.y;
                float n2 = (xac[i][rg][2] - mu) * ri * gg.z + bb.z;
                float n3 = (xac[i][rg][3] - mu) * ri * gg.w + bb.w;
                xac[i][rg][0] = n0; xac[i][rg][1] = n1; xac[i][rg][2] = n2; xac[i][rg][3] = n3;
                s2 += n0 + n1 + n2 + n3;
                q2 += n0 * n0 + n1 * n1 + n2 * n2 + n3 * n3;
            }
            s2 += __shfl_xor(s2, 16); q2 += __shfl_xor(q2, 16);
            s2 += __shfl_xor(s2, 32); q2 += __shfl_xor(q2, 32);
            if (g == 0) { lnS2[rg * 16 + c][w] = s2; lnQ2[rg * 16 + c][w] = q2; }
        }
        __syncthreads();
        // ---- apply LN2, pack n2 -> xb B-frags, init accumulator with b2 ----
#pragma unroll
        for (int rg = 0; rg < 4; ++rg) {
            float4 S = *(const float4*)lnS2[rg * 16 + c];
            float4 Q = *(const float4*)lnQ2[rg * 16 + c];
            float mu = (S.x + S.y + S.z + S.w) * (1.f / 192.f);
            float var = (Q.x + Q.y + Q.z + Q.w) * (1.f / 192.f) - mu * mu;
            float ri = rsqrtf(var + EPS_);
#pragma unroll
            for (int i = 0; i < 3; ++i) {
                int et = w + 4 * i;
                int e0 = et * 16 + g * 4;
                float4 gg = *(const float4*)(ln2g + l * 192 + e0);
                float4 bb = *(const float4*)(ln2b + l * 192 + e0);
                float y0 = (xac[i][rg][0] - mu) * ri * gg.x + bb.x;
                float y1 = (xac[i][rg][1] - mu) * ri * gg.y + bb.y;
                float y2 = (xac[i][rg][2] - mu) * ri * gg.z + bb.z;
                float y3 = (xac[i][rg][3] - mu) * ri * gg.w + bb.w;
                uint_t d0 = cvtpk(y0, y1), d1 = cvtpk(y2, y3);
                int kc = et >> 1, floc = ((et & 1) << 4) + g * 4;
                int us = (kc * 4 + rg) * 512 + ((floc >> 3) * 16 + c) * 8 + (floc & 7);
                *(uint2*)(xb + us) = make_uint2(d0, d1);
                // init accumulator with bias2 (replaces end-of-layer bias add)
                float4 b2v = *(const float4*)(b2g + l * 192 + e0);
                xac[i][rg][0] = b2v.x; xac[i][rg][1] = b2v.y;
                xac[i][rg][2] = b2v.z; xac[i][rg][3] = b2v.w;
            }
        }
        __syncthreads();

        // ---- FFN: two f-halves of 384 ----
#pragma unroll 1
        for (int half = 0; half < 2; ++half) {
            // gemm1: wave's 96-f slice, weights global->reg, x from LDS
            const ushort_t* w1p = w1s + ((size_t)((l * 2 + half) * 4 + w) * 36) * 512 + lane * 8;
#pragma unroll
            for (int fth = 0; fth < 2; ++fth) {
                short8 wa[18];
#pragma unroll
                for (int q = 0; q < 18; ++q) wa[q] = *(const short8*)(w1p + (fth * 18 + q) * 512);
                float4 bbv[3];
#pragma unroll
                for (int f3 = 0; f3 < 3; ++f3)
                    bbv[f3] = *(const float4*)(b1g + l * 768 + half * 384 + w * 96 + (fth * 3 + f3) * 16 + g * 4);
#pragma unroll
                for (int rg = 0; rg < 4; ++rg) {
                    short8 xbf[6];
#pragma unroll
                    for (int kc = 0; kc < 6; ++kc)
                        xbf[kc] = *(const short8*)(xb + (kc * 4 + rg) * 512 + lane * 8);
#pragma unroll
                    for (int f3 = 0; f3 < 3; ++f3) {
                        // bias preloaded into the accumulator (C-in of MFMA)
                        f32x4 acc;
                        acc[0] = bbv[f3].x; acc[1] = bbv[f3].y;
                        acc[2] = bbv[f3].z; acc[3] = bbv[f3].w;
                        __builtin_amdgcn_s_setprio(1);
#pragma unroll
                        for (int kc = 0; kc < 6; ++kc)
                            acc = __builtin_amdgcn_mfma_f32_16x16x32_bf16(wa[f3 * 6 + kc], xbf[kc], acc, 0, 0, 0);
                        __builtin_amdgcn_s_setprio(0);
                        float y0 = fmaxf(acc[0], 0.f);
                        float y1 = fmaxf(acc[1], 0.f);
                        float y2 = fmaxf(acc[2], 0.f);
                        float y3 = fmaxf(acc[3], 0.f);
                        uint_t d0 = cvtpk(y0, y1), d1 = cvtpk(y2, y3);
                        int ft = fth * 3 + f3;
                        int kc2 = w * 3 + (ft >> 1);
                        int floc = ((ft & 1) << 4) + g * 4;
                        int us = (kc2 * 4 + rg) * 512 + ((floc >> 3) * 16 + c) * 8 + (floc & 7);
                        *(uint2*)(hbl + us) = make_uint2(d0, d1);
                    }
                }
            }
            __syncthreads();

            // gemm2: wave's 48-e slice, weights global->reg, h from LDS
            const ushort_t* w2p = w2s + ((size_t)((l * 2 + half) * 4 + w) * 36) * 512 + lane * 8;
#pragma unroll
            for (int kh = 0; kh < 2; ++kh) {
                short8 wr[18];
#pragma unroll
                for (int ei = 0; ei < 3; ++ei)
#pragma unroll
                    for (int k6 = 0; k6 < 6; ++k6)
                        wr[ei * 6 + k6] = *(const short8*)(w2p + (ei * 12 + kh * 6 + k6) * 512);
#pragma unroll
                for (int rg = 0; rg < 4; ++rg) {
                    short8 hbf[6];
#pragma unroll
                    for (int k6 = 0; k6 < 6; ++k6)
                        hbf[k6] = *(const short8*)(hbl + ((kh * 6 + k6) * 4 + rg) * 512 + lane * 8);
                    __builtin_amdgcn_s_setprio(1);
#pragma unroll
                    for (int ei = 0; ei < 3; ++ei)
#pragma unroll
                        for (int k6 = 0; k6 < 6; ++k6)
                            xac[ei][rg] = __builtin_amdgcn_mfma_f32_16x16x32_bf16(wr[ei * 6 + k6], hbf[k6], xac[ei][rg], 0, 0, 0);
                    __builtin_amdgcn_s_setprio(0);
                }
            }
            // barrier only between halves (hbl WAR); end-of-layer barrier is
            // redundant — next hbl write is >=3 barriers away (LN phases)
            if (half == 0) __syncthreads();
        }
        // (bias2 already in accumulator via init)
    }

    // ---- final LN (single) ----
#pragma unroll
    for (int rg = 0; rg < 4; ++rg) {
        float s = 0.f, sq = 0.f;
#pragma unroll
        for (int i = 0; i < 3; ++i)
#pragma unroll
            for (int r = 0; r < 4; ++r) { float v = xac[i][rg][r]; s += v; sq += v * v; }
        s += __shfl_xor(s, 16); sq += __shfl_xor(sq, 16);
        s += __shfl_xor(s, 32); sq += __shfl_xor(sq, 32);
        if (g == 0) { lnS1[rg * 16 + c][w] = s; lnQ1[rg * 16 + c][w] = sq; }
    }
    __syncthreads();
#pragma unroll
    for (int rg = 0; rg < 4; ++rg) {
        float4 S = *(const float4*)lnS1[rg * 16 + c];
        float4 Q = *(const float4*)lnQ1[rg * 16 + c];
        float mu = (S.x + S.y + S.z + S.w) * (1.f / 192.f);
        float var = (Q.x + Q.y + Q.z + Q.w) * (1.f / 192.f) - mu * mu;
        float ri = rsqrtf(var + EPS_);
#pragma unroll
        for (int i = 0; i < 3; ++i) {
            int et = w + 4 * i;
            int e0 = et * 16 + g * 4;
            float4 gg = *(const float4*)(fng + e0);
            float4 bb = *(const float4*)(fnb + e0);
            float y0 = (xac[i][rg][0] - mu) * ri * gg.x + bb.x;
            float y1 = (xac[i][rg][1] - mu) * ri * gg.y + bb.y;
            float y2 = (xac[i][rg][2] - mu) * ri * gg.z + bb.z;
            float y3 = (xac[i][rg][3] - mu) * ri * gg.w + bb.w;
            uint_t d0 = cvtpk(y0, y1), d1 = cvtpk(y2, y3);
            int kc = et >> 1, floc = ((et & 1) << 4) + g * 4;
            int us = (kc * 4 + rg) * 512 + ((floc >> 3) * 16 + c) * 8 + (floc & 7);
            *(uint2*)(xb + us) = make_uint2(d0, d1);
        }
    }
    __syncthreads();

    // ---- head: wave w handles rows rg=w (16 rows), all 96 vocab ----
    short8 wfh[36];
    {
        const ushort_t* wfp = wfr + lane * 8;
#pragma unroll
        for (int q = 0; q < 36; ++q) wfh[q] = *(const short8*)(wfp + q * 512);
    }
    short8 xbf[6];
#pragma unroll
    for (int kc = 0; kc < 6; ++kc)
        xbf[kc] = *(const short8*)(xb + (kc * 4 + w) * 512 + lane * 8);
    f32x4 av[6] = {};
    __builtin_amdgcn_s_setprio(1);
#pragma unroll
    for (int vt = 0; vt < 6; ++vt)
#pragma unroll
        for (int kc = 0; kc < 6; ++kc)
            av[vt] = __builtin_amdgcn_mfma_f32_16x16x32_bf16(wfh[vt * 6 + kc], xbf[kc], av[vt], 0, 0, 0);
    __builtin_amdgcn_s_setprio(0);

    float vv[6][4];
#pragma unroll
    for (int vt = 0; vt < 6; ++vt) {
        float4 bb = *(const float4*)(bfb + vt * 16 + g * 4);
        vv[vt][0] = av[vt][0] + bb.x;
        vv[vt][1] = av[vt][1] + bb.y;
        vv[vt][2] = av[vt][2] + bb.z;
        vv[vt][3] = av[vt][3] + bb.w;
    }
    float mx = -1e30f;
#pragma unroll
    for (int vt = 0; vt < 6; ++vt)
#pragma unroll
        for (int r = 0; r < 4; ++r) mx = fmaxf(mx, vv[vt][r]);
    mx = fmaxf(mx, __shfl_xor(mx, 16));
    mx = fmaxf(mx, __shfl_xor(mx, 32));
    float se = 0.f;
#pragma unroll
    for (int vt = 0; vt < 6; ++vt)
#pragma unroll
        for (int r = 0; r < 4; ++r) se += expf(vv[vt][r] - mx);
    se += __shfl_xor(se, 16);
    se += __shfl_xor(se, 32);
    float lse = logf(se) + mx;
    int myrow = row0 + w * 16 + c;
    int tgt = tgp[myrow];
    float lsum = 0.f;
#pragma unroll
    for (int vt = 0; vt < 6; ++vt)
#pragma unroll
        for (int r = 0; r < 4; ++r)
            if (tgt == vt * 16 + g * 4 + r) lsum += lse - vv[vt][r];
#pragma unroll
    for (int vt = 0; vt < 6; ++vt) {
        float4 o;
        o.x = vv[vt][0]; o.y = vv[vt][1]; o.z = vv[vt][2]; o.w = vv[vt][3];
        *(float4*)(pred + (size_t)myrow * 96 + vt * 16 + g * 4) = o;
    }
#pragma unroll
    for (int m = 1; m < 64; m <<= 1) lsum += __shfl_xor(lsum, m);
    if (lane == 0) lsred[w] = lsum;
    __syncthreads();
    if (tid == 0) partial[blockIdx.x] = lsred[0] + lsred[1] + lsred[2] + lsred[3];
}

__global__ void lossred_k(const float* __restrict__ partial, float* __restrict__ out)
{
    __shared__ double sd[256];
    int t = threadIdx.x;
    sd[t] = (double)partial[t] + (double)partial[t + 256];
    __syncthreads();
    for (int s = 128; s > 0; s >>= 1) {
        if (t < s) sd[t] += sd[t + s];
        __syncthreads();
    }
    if (t == 0) out[0] = (float)(sd[0] / (double)R_);
}

extern "C" void kernel_launch(void* const* d_in, const int* in_sizes, int n_in,
                              void* d_out, int out_size, void* d_ws, size_t ws_size,
                              hipStream_t stream)
{
    (void)in_sizes; (void)n_in; (void)out_size; (void)ws_size;
    const int*   index   = (const int*)  d_in[0];
    const int*   targets = (const int*)  d_in[1];
    const float* tok     = (const float*)d_in[2];
    const float* pos     = (const float*)d_in[3];
    const float* ln1g    = (const float*)d_in[4];
    const float* ln1b    = (const float*)d_in[5];
    const float* ln2g    = (const float*)d_in[6];
    const float* ln2b    = (const float*)d_in[7];
    // d_in[8..10] = Wq/Wk/Wv: dead in the reference forward
    const float* W1      = (const float*)d_in[11];
    const float* b1      = (const float*)d_in[12];
    const float* W2      = (const float*)d_in[13];
    const float* b2      = (const float*)d_in[14];
    const float* fng     = (const float*)d_in[15];
    const float* fnb     = (const float*)d_in[16];
    const float* Wf      = (const float*)d_in[17];
    const float* bfv     = (const float*)d_in[18];

    ushort_t* w1s = (ushort_t*)d_ws;                        // [884736]
    ushort_t* w2s = w1s + NW_;                              // [884736]
    ushort_t* wfr = w2s + NW_;                              // [18432]
    float* partial = (float*)(wfr + 36 * 512);              // [512]
    float* pred  = (float*)d_out;
    float* lossp = pred + (size_t)R_ * 96;

    const int nconv = 2 * NW_ + 36 * 512;                   // 1787904 = 6984*256
    wconv_k<<<nconv / 256, 256, 0, stream>>>(W1, W2, Wf, w1s, w2s, wfr);
    net_k<<<512, 256, 0, stream>>>(index, targets, tok, pos, ln1g, ln1b, ln2g, ln2b,
                                   b1, b2, fng, fnb, bfv, w1s, w2s, wfr, pred, partial);
    lossred_k<<<1, 256, 0, stream>>>(partial, lossp);
}